// Round 2
// baseline (200.061 us; speedup 1.0000x reference)
//
#include <hip/hip_runtime.h>
#include <math.h>

#define BB 64
#define LL 512
#define SS 512
#define HH 768
#define CC 9
#define WPW 4                       // words per wave
#define WPB 16                      // words per block (4 waves)
#define GF (BB * SS / WPB)          // 2048 fused blocks
#define NPART (GF * 4)              // 8192 per-wave partials

// DPP full-wave (64-lane) sum; total lands in lane 63. Pure VALU, no LDS.
template <int CTRL>
__device__ __forceinline__ float dpp_add(float x) {
    int y = __builtin_amdgcn_update_dpp(0, __float_as_int(x), CTRL, 0xf, 0xf, true);
    return x + __int_as_float(y);
}
__device__ __forceinline__ float rsum64(float x) {
    x = dpp_add<0x111>(x);  // row_shr:1
    x = dpp_add<0x112>(x);  // row_shr:2
    x = dpp_add<0x114>(x);  // row_shr:4
    x = dpp_add<0x118>(x);  // row_shr:8
    x = dpp_add<0x142>(x);  // row_bcast:15
    x = dpp_add<0x143>(x);  // row_bcast:31 -> lane 63 = full sum
    return x;
}

__device__ __forceinline__ float4 f4add(float4 a, float4 b) {
    return make_float4(a.x + b.x, a.y + b.y, a.z + b.z, a.w + b.w);
}
__device__ __forceinline__ float dot4(float4 a, float4 b) {
    return a.x * b.x + a.y * b.y + a.z * b.z + a.w * b.w;
}

// Kernel 0: W[H][C] -> WT[C][H] in ws (27 KB, L2-resident after)
__global__ __launch_bounds__(256) void wt_kernel(const float* __restrict__ Wm,
                                                 float* __restrict__ WT_g) {
    int e = blockIdx.x * 256 + threadIdx.x;
    if (e < HH * CC) {
        int h = e / CC;
        int c = e - h * CC;
        WT_g[c * HH + h] = Wm[e];
    }
}

// Kernel 1: pool-first fused kernel. Per wave: 4 consecutive words.
// Inner loop = 12 adds/row (pool in H-space); 9-class dot ONCE per word
// with W read from LDS (no 108-reg W tile -> no spill).
__global__ __launch_bounds__(256, 2) void fused_kernel(
    const float* __restrict__ bert,      // [B*L, H]
    const float* __restrict__ WT_g,      // [C][H]
    const float* __restrict__ bias,      // [C]
    const int* __restrict__ ids_lens,    // [B, S]
    const int* __restrict__ label_ids,   // [B, S]
    float* __restrict__ pred_out,        // d_out + 1
    float* __restrict__ nll_part,        // [NPART]
    float* __restrict__ cnt_part)        // [NPART]
{
    __shared__ float wt_sh[CC * HH];     // 27648 B
    __shared__ int wlen[WPB];
    __shared__ int woff[WPB + 1];
    __shared__ float red[4];
    __shared__ int s_start_sh;

    int b = blockIdx.x >> 5;             // 32 blocks per batch
    int chunk = blockIdx.x & 31;
    int w0 = chunk * WPB;
    const int* lens = ids_lens + b * SS;
    int t = threadIdx.x, lane = t & 63, wave = t >> 6;

    if (t < WPB) wlen[t] = lens[w0 + t];

    // rows before this block's slice (ints < 1536: exact in f32)
    int part = 0;
    for (int i = t; i < w0; i += 256) part += lens[i];
    float pf = rsum64((float)part);
    if (lane == 63) red[wave] = pf;
    __syncthreads();
    if (t == 0) {
        int run = 0;
#pragma unroll
        for (int k = 0; k < WPB; k++) { woff[k] = run; run += wlen[k]; }
        woff[WPB] = run;
        s_start_sh = (int)(red[0] + red[1] + red[2] + red[3]);
    }
    __syncthreads();

    int tot_rows = woff[WPB];
    if (tot_rows == 0) {
        // all 16 words empty: logits = bias -> pred = argmax(bias); no loss
        if (t < WPB) {
            float mx = bias[0]; int arg = 0;
#pragma unroll
            for (int c = 1; c < CC; c++) { float v = bias[c]; if (v > mx) { mx = v; arg = c; } }
            pred_out[b * SS + w0 + t] = (float)arg;
        }
        if (t < 4) { nll_part[blockIdx.x * 4 + t] = 0.0f; cnt_part[blockIdx.x * 4 + t] = 0.0f; }
        return;
    }

    // stage WT into LDS (coalesced float4; 1728 float4)
    {
        const float4* src = reinterpret_cast<const float4*>(WT_g);
        float4* dst = reinterpret_cast<float4*>(wt_sh);
#pragma unroll
        for (int i = 0; i < 7; i++) {
            int idx = t + i * 256;
            if (idx < (CC * HH / 4)) dst[idx] = src[idx];
        }
    }
    __syncthreads();

    float bsr[CC];
#pragma unroll
    for (int c = 0; c < CC; c++) bsr[c] = bias[c];

    int hoff = lane * 4;
    int w8 = wave * WPW;
    size_t rowbase = (size_t)b * LL + (size_t)s_start_sh;
    float nll_acc = 0.0f, cnt_acc = 0.0f;

    // double-buffered row prefetch: 2 sets x 3 rows x 3 float4 chunks
    float4 a00, a01, a02, a10, a11, a12, a20, a21, a22;
    float4 b00, b01, b02, b10, b11, b12, b20, b21, b22;

#define LDROW(pb_, r_, ch_) (*reinterpret_cast<const float4*>((pb_) + (size_t)(r_) * HH + (ch_) * 256))
#define ISSUE(P0, P1, P2, P3, P4, P5, P6, P7, P8, KN) do {                         \
    int ln_ = wlen[w8 + (KN)];                                                     \
    const float* pb_ = bert + (rowbase + (size_t)woff[w8 + (KN)]) * HH + hoff;     \
    if (ln_ > 0) { P0 = LDROW(pb_, 0, 0); P1 = LDROW(pb_, 0, 1); P2 = LDROW(pb_, 0, 2); } \
    if (ln_ > 1) { P3 = LDROW(pb_, 1, 0); P4 = LDROW(pb_, 1, 1); P5 = LDROW(pb_, 1, 2); } \
    if (ln_ > 2) { P6 = LDROW(pb_, 2, 0); P7 = LDROW(pb_, 2, 1); P8 = LDROW(pb_, 2, 2); } \
} while (0)

#define EPI(Q0, Q1, Q2, Q3, Q4, Q5, Q6, Q7, Q8, KN) do {                           \
    int len_ = wlen[w8 + (KN)];                                                    \
    float acc_[CC];                                                                \
    if (len_ > 0) {                                                                \
        float4 s0_ = Q0, s1_ = Q1, s2_ = Q2;                                       \
        if (len_ > 1) { s0_ = f4add(s0_, Q3); s1_ = f4add(s1_, Q4); s2_ = f4add(s2_, Q5); } \
        if (len_ > 2) { s0_ = f4add(s0_, Q6); s1_ = f4add(s1_, Q7); s2_ = f4add(s2_, Q8); } \
        _Pragma("unroll")                                                          \
        for (int c = 0; c < CC; c++) {                                             \
            float4 w0_ = *reinterpret_cast<const float4*>(&wt_sh[c * HH + hoff]);         \
            float4 w1_ = *reinterpret_cast<const float4*>(&wt_sh[c * HH + 256 + hoff]);   \
            float4 w2_ = *reinterpret_cast<const float4*>(&wt_sh[c * HH + 512 + hoff]);   \
            acc_[c] = dot4(s0_, w0_) + dot4(s1_, w1_) + dot4(s2_, w2_);            \
        }                                                                          \
        _Pragma("unroll")                                                          \
        for (int c = 0; c < CC; c++) acc_[c] = rsum64(acc_[c]);                    \
    } else {                                                                       \
        _Pragma("unroll")                                                          \
        for (int c = 0; c < CC; c++) acc_[c] = 0.0f;                               \
    }                                                                              \
    if (lane == 63) {                                                              \
        float inv_ = (len_ > 0) ? (1.0f / (float)len_) : 1.0f;                     \
        float lg_[CC];                                                             \
        _Pragma("unroll")                                                          \
        for (int c = 0; c < CC; c++) lg_[c] = acc_[c] * inv_ + bsr[c];             \
        float mx_ = lg_[0]; int arg_ = 0;                                          \
        _Pragma("unroll")                                                          \
        for (int c = 1; c < CC; c++) { if (lg_[c] > mx_) { mx_ = lg_[c]; arg_ = c; } } \
        float se_ = 0.0f;                                                          \
        _Pragma("unroll")                                                          \
        for (int c = 0; c < CC; c++) se_ += expf(lg_[c] - mx_);                    \
        float lse_ = mx_ + logf(se_);                                              \
        int g_ = b * SS + w0 + w8 + (KN);                                          \
        int lab_ = label_ids[g_];                                                  \
        lab_ = lab_ < 0 ? 0 : (lab_ > CC - 1 ? CC - 1 : lab_);                     \
        if (len_ > 0) { nll_acc += lse_ - lg_[lab_]; cnt_acc += 1.0f; }            \
        pred_out[g_] = (float)arg_;                                                \
    }                                                                              \
} while (0)

    // software pipeline: issue word k+1's rows before consuming word k
    ISSUE(a00, a01, a02, a10, a11, a12, a20, a21, a22, 0);
    ISSUE(b00, b01, b02, b10, b11, b12, b20, b21, b22, 1);
    EPI(a00, a01, a02, a10, a11, a12, a20, a21, a22, 0);
    ISSUE(a00, a01, a02, a10, a11, a12, a20, a21, a22, 2);
    EPI(b00, b01, b02, b10, b11, b12, b20, b21, b22, 1);
    ISSUE(b00, b01, b02, b10, b11, b12, b20, b21, b22, 3);
    EPI(a00, a01, a02, a10, a11, a12, a20, a21, a22, 2);
    EPI(b00, b01, b02, b10, b11, b12, b20, b21, b22, 3);

#undef EPI
#undef ISSUE
#undef LDROW

    if (lane == 63) {
        nll_part[blockIdx.x * 4 + wave] = nll_acc;
        cnt_part[blockIdx.x * 4 + wave] = cnt_acc;
    }
}

// Kernel 2: deterministic reduction of 8192 per-wave partials -> loss
__global__ __launch_bounds__(1024) void finalize_kernel(
    const float* __restrict__ nll_part,
    const float* __restrict__ cnt_part,
    float* __restrict__ out_loss) {
    __shared__ float sn[16], sc[16];
    int t = threadIdx.x, lane = t & 63, wave = t >> 6;
    float n = 0.0f, c = 0.0f;
#pragma unroll
    for (int i = 0; i < NPART / 1024; ++i) {
        n += nll_part[t + i * 1024];
        c += cnt_part[t + i * 1024];
    }
    n = rsum64(n);
    c = rsum64(c);
    if (lane == 63) { sn[wave] = n; sc[wave] = c; }
    __syncthreads();
    if (t == 0) {
        float tn = 0.0f, tc = 0.0f;
#pragma unroll
        for (int i = 0; i < 16; i++) { tn += sn[i]; tc += sc[i]; }
        out_loss[0] = tn / fmaxf(tc, 1.0f);
    }
}

extern "C" void kernel_launch(void* const* d_in, const int* in_sizes, int n_in,
                              void* d_out, int out_size, void* d_ws, size_t ws_size,
                              hipStream_t stream) {
    const float* bert = (const float*)d_in[0]; // float32 [B,L,H]
    const float* Wm   = (const float*)d_in[1]; // float32 [H,C]
    const float* bias = (const float*)d_in[2]; // float32 [C]
    // d_in[3] = attention_mask (unused: prefix mask implied by ids_lens)
    const int* ids_lens  = (const int*)d_in[4];
    const int* label_ids = (const int*)d_in[5];
    // d_in[6] = label_mask (derived from ids_lens > 0)

    float* out = (float*)d_out;  // [0]=loss, [1..32768]=pred, float32

    float* WT_g     = (float*)d_ws;            // [C][H]  27648 B
    float* nll_part = WT_g + CC * HH;          // [NPART]
    float* cnt_part = nll_part + NPART;        // [NPART]

    wt_kernel<<<(HH * CC + 255) / 256, 256, 0, stream>>>(Wm, WT_g);
    fused_kernel<<<GF, 256, 0, stream>>>(bert, WT_g, bias, ids_lens, label_ids,
                                         out + 1, nll_part, cnt_part);
    finalize_kernel<<<1, 1024, 0, stream>>>(nll_part, cnt_part, out);
}

// Round 3
// 179.704 us; speedup vs baseline: 1.1133x; 1.1133x over previous
//
#include <hip/hip_runtime.h>
#include <math.h>

#define BB 64
#define LL 512
#define SS 512
#define HH 768
#define CC 9
#define WPV 2                       // words per wave
#define WPB (WPV * 4)               // 8 words per block (4 waves)
#define GW (BB * SS / WPB)          // 4096 word blocks
#define NPART (GW * 4)              // 16384 per-wave partials

// DPP full-wave (64-lane) sum; total lands in lane 63. Pure VALU, no LDS.
template <int CTRL>
__device__ __forceinline__ float dpp_add(float x) {
    int y = __builtin_amdgcn_update_dpp(0, __float_as_int(x), CTRL, 0xf, 0xf, true);
    return x + __int_as_float(y);
}
__device__ __forceinline__ float rsum64(float x) {
    x = dpp_add<0x111>(x);  // row_shr:1
    x = dpp_add<0x112>(x);  // row_shr:2
    x = dpp_add<0x114>(x);  // row_shr:4
    x = dpp_add<0x118>(x);  // row_shr:8
    x = dpp_add<0x142>(x);  // row_bcast:15
    x = dpp_add<0x143>(x);  // row_bcast:31 -> lane 63 = full sum
    return x;
}

__device__ __forceinline__ float4 f4add(float4 a, float4 b) {
    return make_float4(a.x + b.x, a.y + b.y, a.z + b.z, a.w + b.w);
}
__device__ __forceinline__ float dot4(float4 a, float4 b) {
    return a.x * b.x + a.y * b.y + a.z * b.z + a.w * b.w;
}

// Kernel 0: blocks 0..63 = per-batch exclusive scan of ids_lens -> woff;
//           block 64     = W[H][C] -> WT[C][H] transpose.
__global__ __launch_bounds__(512) void scan_wt_kernel(
    const int* __restrict__ ids_lens,   // [B, S]
    const float* __restrict__ Wm,       // [H, C]
    int* __restrict__ woff_g,           // [B, S] start row of each word
    float* __restrict__ WT_g)           // [C, H]
{
    if (blockIdx.x == BB) {
        for (int e = threadIdx.x; e < HH * CC; e += 512) {
            int h = e / CC;
            int c = e - h * CC;
            WT_g[c * HH + h] = Wm[e];
        }
        return;
    }
    __shared__ int wtot[8];
    int b = blockIdx.x;
    int t = threadIdx.x, lane = t & 63, wave = t >> 6;
    int len = ids_lens[b * SS + t];
    int x = len;                         // wave-level inclusive scan (exact int)
#pragma unroll
    for (int off = 1; off < 64; off <<= 1) {
        int y = __shfl_up(x, off);
        if (lane >= off) x += y;
    }
    if (lane == 63) wtot[wave] = x;
    __syncthreads();
    int base = 0;
    for (int wv = 0; wv < wave; wv++) base += wtot[wv];
    woff_g[b * SS + t] = base + x - len; // exclusive scan = start row
}

// Kernel 1: word-indexed hot kernel. NO LDS, NO barriers.
// Wave owns 2 words: pool <=3 rows in regs, c-outer dot vs L1-resident WT,
// 9 rsum64 per word, softmax/NLL/pred on lane 63.
__global__ __launch_bounds__(256, 4) void word_kernel(
    const float* __restrict__ bert,      // [B*L, H]
    const float* __restrict__ WT_g,      // [C][H]
    const float* __restrict__ bias,      // [C]
    const int* __restrict__ ids_lens,    // [B*S]
    const int* __restrict__ woff_g,      // [B*S]
    const int* __restrict__ label_ids,   // [B*S]
    float* __restrict__ pred_out,        // d_out + 1
    float* __restrict__ nll_part,        // [NPART]
    float* __restrict__ cnt_part)        // [NPART]
{
    int t = threadIdx.x, lane = t & 63, wave = t >> 6;
    int hoff = lane * 4;
    int gA = blockIdx.x * WPB + wave * WPV;  // first of the wave's 2 words
    int gB = gA + 1;
    int pid = blockIdx.x * 4 + wave;

    int lenA = ids_lens[gA];
    int lenB = ids_lens[gB];

    float bs[CC];
#pragma unroll
    for (int c = 0; c < CC; c++) bs[c] = bias[c];

    if ((lenA | lenB) == 0) {            // ~40% of waves: logits = bias
        if (lane == 63) {
            float mx = bs[0]; int arg = 0;
#pragma unroll
            for (int c = 1; c < CC; c++) { if (bs[c] > mx) { mx = bs[c]; arg = c; } }
            pred_out[gA] = (float)arg;
            pred_out[gB] = (float)arg;
            nll_part[pid] = 0.0f;
            cnt_part[pid] = 0.0f;
        }
        return;
    }

    const float4 z4 = make_float4(0.f, 0.f, 0.f, 0.f);
    float4 PA0 = z4, PA1 = z4, PA2 = z4;
    float4 PB0 = z4, PB1 = z4, PB2 = z4;

#define LD3(dst0, dst1, dst2, base_, r_)                                         \
    do {                                                                         \
        const float* q_ = (base_) + (size_t)(r_) * HH;                           \
        dst0 = *reinterpret_cast<const float4*>(q_);                             \
        dst1 = *reinterpret_cast<const float4*>(q_ + 256);                       \
        dst2 = *reinterpret_cast<const float4*>(q_ + 512);                       \
    } while (0)

    {   // pool word A (rows contiguous from its start row)
        int bA = gA >> 9;
        const float* pA = bert + ((size_t)bA * LL + woff_g[gA]) * HH + hoff;
        float4 r0a, r1a, r2a, r0b, r1b, r2b, r0c, r1c, r2c;
        if (lenA > 0) LD3(r0a, r1a, r2a, pA, 0);
        if (lenA > 1) LD3(r0b, r1b, r2b, pA, 1);
        if (lenA > 2) LD3(r0c, r1c, r2c, pA, 2);
        if (lenA > 0) { PA0 = r0a; PA1 = r1a; PA2 = r2a; }
        if (lenA > 1) { PA0 = f4add(PA0, r0b); PA1 = f4add(PA1, r1b); PA2 = f4add(PA2, r2b); }
        if (lenA > 2) { PA0 = f4add(PA0, r0c); PA1 = f4add(PA1, r1c); PA2 = f4add(PA2, r2c); }
    }
    {   // pool word B
        int bB = gB >> 9;
        const float* pB = bert + ((size_t)bB * LL + woff_g[gB]) * HH + hoff;
        float4 r0a, r1a, r2a, r0b, r1b, r2b, r0c, r1c, r2c;
        if (lenB > 0) LD3(r0a, r1a, r2a, pB, 0);
        if (lenB > 1) LD3(r0b, r1b, r2b, pB, 1);
        if (lenB > 2) LD3(r0c, r1c, r2c, pB, 2);
        if (lenB > 0) { PB0 = r0a; PB1 = r1a; PB2 = r2a; }
        if (lenB > 1) { PB0 = f4add(PB0, r0b); PB1 = f4add(PB1, r1b); PB2 = f4add(PB2, r2b); }
        if (lenB > 2) { PB0 = f4add(PB0, r0c); PB1 = f4add(PB1, r1c); PB2 = f4add(PB2, r2c); }
    }
#undef LD3

    // c-outer: stream W once per 2 words (L1-hot 27 KB), dot both pooled sums
    float accA[CC], accB[CC];
#pragma unroll
    for (int c = 0; c < CC; c++) {
        float4 w0 = *reinterpret_cast<const float4*>(WT_g + c * HH + hoff);
        float4 w1 = *reinterpret_cast<const float4*>(WT_g + c * HH + 256 + hoff);
        float4 w2 = *reinterpret_cast<const float4*>(WT_g + c * HH + 512 + hoff);
        accA[c] = dot4(PA0, w0) + dot4(PA1, w1) + dot4(PA2, w2);
        accB[c] = dot4(PB0, w0) + dot4(PB1, w1) + dot4(PB2, w2);
    }
#pragma unroll
    for (int c = 0; c < CC; c++) {
        accA[c] = rsum64(accA[c]);       // 18 independent 6-step DPP chains
        accB[c] = rsum64(accB[c]);
    }

    if (lane == 63) {
        float nll_acc = 0.0f, cnt_acc = 0.0f;
#pragma unroll
        for (int wsel = 0; wsel < 2; wsel++) {
            int g = wsel ? gB : gA;
            int len = wsel ? lenB : lenA;
            float inv = (len > 0) ? (1.0f / (float)len) : 1.0f;
            float lg[CC];
#pragma unroll
            for (int c = 0; c < CC; c++)
                lg[c] = (wsel ? accB[c] : accA[c]) * inv + bs[c];
            float mx = lg[0]; int arg = 0;
#pragma unroll
            for (int c = 1; c < CC; c++) { if (lg[c] > mx) { mx = lg[c]; arg = c; } }
            float se = 0.0f;
#pragma unroll
            for (int c = 0; c < CC; c++) se += expf(lg[c] - mx);
            float lse = mx + logf(se);
            int lab = label_ids[g];
            lab = lab < 0 ? 0 : (lab > CC - 1 ? CC - 1 : lab);
            if (len > 0) { nll_acc += lse - lg[lab]; cnt_acc += 1.0f; }
            pred_out[g] = (float)arg;
        }
        nll_part[pid] = nll_acc;
        cnt_part[pid] = cnt_acc;
    }
}

// Kernel 2: deterministic reduction of 16384 per-wave partials -> loss
__global__ __launch_bounds__(1024) void finalize_kernel(
    const float* __restrict__ nll_part,
    const float* __restrict__ cnt_part,
    float* __restrict__ out_loss) {
    __shared__ float sn[16], sc[16];
    int t = threadIdx.x, lane = t & 63, wave = t >> 6;
    float n = 0.0f, c = 0.0f;
#pragma unroll
    for (int i = 0; i < NPART / 1024; ++i) {
        n += nll_part[t + i * 1024];
        c += cnt_part[t + i * 1024];
    }
    n = rsum64(n);
    c = rsum64(c);
    if (lane == 63) { sn[wave] = n; sc[wave] = c; }
    __syncthreads();
    if (t == 0) {
        float tn = 0.0f, tc = 0.0f;
#pragma unroll
        for (int i = 0; i < 16; i++) { tn += sn[i]; tc += sc[i]; }
        out_loss[0] = tn / fmaxf(tc, 1.0f);
    }
}

extern "C" void kernel_launch(void* const* d_in, const int* in_sizes, int n_in,
                              void* d_out, int out_size, void* d_ws, size_t ws_size,
                              hipStream_t stream) {
    const float* bert = (const float*)d_in[0]; // float32 [B,L,H]
    const float* Wm   = (const float*)d_in[1]; // float32 [H,C]
    const float* bias = (const float*)d_in[2]; // float32 [C]
    // d_in[3] = attention_mask (unused: prefix mask implied by ids_lens)
    const int* ids_lens  = (const int*)d_in[4];
    const int* label_ids = (const int*)d_in[5];
    // d_in[6] = label_mask (derived from ids_lens > 0)

    float* out = (float*)d_out;  // [0]=loss, [1..32768]=pred, float32

    float* WT_g     = (float*)d_ws;                    // [C][H]  27648 B
    int*   woff_g   = (int*)(WT_g + CC * HH);          // [B*S]   128 KB
    float* nll_part = (float*)(woff_g + BB * SS);      // [NPART]
    float* cnt_part = nll_part + NPART;                // [NPART]

    scan_wt_kernel<<<BB + 1, 512, 0, stream>>>(ids_lens, Wm, woff_g, WT_g);
    word_kernel<<<GW, 256, 0, stream>>>(bert, WT_g, bias, ids_lens, woff_g,
                                        label_ids, out + 1, nll_part, cnt_part);
    finalize_kernel<<<1, 1024, 0, stream>>>(nll_part, cnt_part, out);
}